// Round 16
// baseline (104.048 us; speedup 1.0000x reference)
//
#include <hip/hip_runtime.h>
#include <math.h>

#define TT 8192
#define DD 128
#define GB 64
#define GN 128
#define GE 2048

// ---- workspace layout (bytes) ----
#define WS_WG16    0u            // 128KB: 4 x 16384 f16 frag-order GCN weights
#define WS_W2      (644u<<10)    // 128*128 f32
#define WS_B2      (708u<<10)    // 128 f32
#define WS_Q16     (1u<<20)      // 2MB f16
#define WS_K16     (3u<<20)      // 2MB f16 frag-order
#define WS_VT      (5u<<20)      // 2MB f16 frag-order (kappa)
#define WS_OPART   (7u<<20)      // 16MB: 8 x 8192 x 128 f16 partials
#define WS_PM      (23u<<20)     // 8*8192 f32
#define WS_PL      ((23u<<20)+(256u<<10))

typedef _Float16 hfrag  __attribute__((ext_vector_type(8)));
typedef _Float16 h4     __attribute__((ext_vector_type(4)));
typedef float    ffrag  __attribute__((ext_vector_type(4)));

#define MFMA16(a,b,c) __builtin_amdgcn_mfma_f32_16x16x32_f16((a),(b),(c),0,0,0)

typedef __attribute__((address_space(1))) unsigned int gu32_t;
typedef __attribute__((address_space(3))) unsigned int lu32_t;
#define GLOAD16(gp, lp) __builtin_amdgcn_global_load_lds((gu32_t*)(const void*)(gp), (lu32_t*)(void*)(lp), 16, 0, 0)

// fragment-order element index (proven): A-frag = fidx(i,k); B-frag = fidx(j,k)
__device__ __forceinline__ int fidx(int r_, int c_) {
  return (((r_>>4)*4 + (c_>>5))*64 + (r_&15) + 16*((c_>>3)&3))*8 + (c_&7);
}

__device__ __forceinline__ float tanh_fast(float x) {
  float e = __expf(2.f*x);
  return 1.f - 2.f/(e+1.f);
}

// =====================================================================
// k_prep: 8 blocks x 512 threads (unchanged, proven).
// =====================================================================
__global__ __launch_bounds__(512) void k_prep(const float* __restrict__ Wg,
                                              const float* __restrict__ Wo, const float* __restrict__ bo,
                                              const float* __restrict__ Wc, const float* __restrict__ bc,
                                              _Float16* __restrict__ wg16,
                                              float* __restrict__ W2, float* __restrict__ b2) {
  __shared__ float Wcs[128*128];
  const int tid = threadIdx.x;
  const int bid = blockIdx.x;
  if (bid < 4) {
    #pragma unroll
    for (int i=0;i<32;++i){
      int i2 = i*512 + tid;
      Wcs[i2] = Wc[i2] + Wc[i2 + 16384];
    }
    __syncthreads();
    const int r  = tid>>4;
    const int c0 = (tid&15)*8;
    const int ig = bid*32 + r;
    float acc[8];
    #pragma unroll
    for (int m=0;m<8;++m) acc[m]=0.f;
    for (int k=0;k<128;++k){
      float wo = Wo[ig*DD + k];
      #pragma unroll
      for (int m=0;m<8;++m) acc[m] += wo*Wcs[k*128 + c0 + m];
    }
    #pragma unroll
    for (int m=0;m<8;++m) W2[ig*DD + c0 + m] = acc[m];
    if (bid == 0){
      __syncthreads();
      if (tid < 128){
        float s = bc[tid];
        for (int k=0;k<128;++k) s += bo[k]*Wcs[k*128 + tid];
        b2[tid] = s;
      }
    }
  } else {
    const int l = bid - 4;
    const float* Wl = Wg + l*DD*DD;
    _Float16* dst = wg16 + l*16384;
    #pragma unroll
    for (int i=0;i<8;++i){
      int i4 = i*512 + tid;
      int k = i4>>5, i0 = (i4&31)<<2;
      float4 v = *(const float4*)&Wl[k*DD + i0];
      dst[fidx(i0+0,k)] = (_Float16)v.x;
      dst[fidx(i0+1,k)] = (_Float16)v.y;
      dst[fidx(i0+2,k)] = (_Float16)v.z;
      dst[fidx(i0+3,k)] = (_Float16)v.w;
    }
  }
}

// =====================================================================
// fused_pre: 256 blocks x 1024 threads (unchanged from r15, proven).
// =====================================================================
__global__ __launch_bounds__(1024,1) void fused_pre(
    const float* __restrict__ x, const int* __restrict__ edges,
    const _Float16* __restrict__ wg16, const float* __restrict__ bg,
    const float* __restrict__ Wq, const float* __restrict__ bq_,
    const float* __restrict__ Wk, const float* __restrict__ bk_,
    const float* __restrict__ Wv, const float* __restrict__ bv_,
    _Float16* __restrict__ q16, _Float16* __restrict__ k16, _Float16* __restrict__ vT,
    float* __restrict__ out)
{
  __shared__ __align__(16) char Lm[135168];
  const int tid  = threadIdx.x;
  const int bid  = blockIdx.x;

  if (bid < 64) {
    // ---------------- GCN role (16 warps) ----------------
    float*    Af   = (float*)Lm;
    _Float16* W16f = (_Float16*)Lm;
    _Float16* m16  = (_Float16*)(Lm + 32768);
    _Float16* h16  = (_Float16*)(Lm + 65536);
    _Float16* A16  = (_Float16*)(Lm + 98304);
    int*      cnt  = (int*)(Lm + 131072);
    float*    nrm  = (float*)(Lm + 131584);

    const int lane = tid & 63;
    const int w16  = tid >> 6;
    const int l15  = lane & 15;
    const int g    = lane >> 4;
    const int wi   = w16 >> 2;
    const int wj   = w16 & 3;
    const int b    = bid;
    const int* eg  = edges + b*2*GE;

    #pragma unroll
    for (int i=0;i<4;++i) ((float4*)Af)[i*1024 + tid] = (float4){0.f,0.f,0.f,0.f};
    if (tid < 128) cnt[tid] = 0;
    __syncthreads();
    #pragma unroll
    for (int i=0;i<2;++i) atomicAdd(&cnt[eg[GE + i*1024 + tid]], 1);
    __syncthreads();
    if (tid < 128) nrm[tid] = rsqrtf(1.f + (float)cnt[tid]);
    __syncthreads();
    #pragma unroll
    for (int i=0;i<2;++i){
      int s = eg[i*1024 + tid], d = eg[GE + i*1024 + tid];
      atomicAdd(&Af[d*128 + s], nrm[s]*nrm[d]);
    }
    __syncthreads();
    if (tid < 128) Af[tid*128 + tid] += nrm[tid]*nrm[tid];
    __syncthreads();
    #pragma unroll
    for (int i=0;i<4;++i){
      int i4 = i*1024 + tid;
      float4 v = ((const float4*)Af)[i4];
      int dst = i4>>5, s4 = (i4&31)<<2;
      h4 t; t[0]=(_Float16)v.x; t[1]=(_Float16)v.y; t[2]=(_Float16)v.z; t[3]=(_Float16)v.w;
      *(h4*)&A16[fidx(dst, s4)] = t;
    }
    #pragma unroll
    for (int i=0;i<4;++i){
      int i4 = i*1024 + tid;
      int n = i4>>5, k4 = (i4&31)<<2;
      float4 v = *(const float4*)&x[((size_t)b*128 + n)*128 + k4];
      h4 t; t[0]=(_Float16)v.x; t[1]=(_Float16)v.y; t[2]=(_Float16)v.z; t[3]=(_Float16)v.w;
      *(h4*)&h16[fidx(n, k4)] = t;
    }
    __syncthreads();
    #pragma unroll
    for (int i=0;i<2;++i){
      const int c = i*16 + w16;
      GLOAD16(wg16 + c*512 + lane*8, &W16f[c*512]);
    }
    asm volatile("s_waitcnt vmcnt(0)" ::: "memory");
    __syncthreads();

    for (int l=0; l<4; ++l){
      {
        hfrag bf[2][4];
        #pragma unroll
        for (int jj=0;jj<2;++jj){
          const int jg = wj*2+jj;
          #pragma unroll
          for (int ds=0;ds<4;++ds) bf[jj][ds] = *(const hfrag*)&h16[(jg*4+ds)*512 + lane*8];
        }
        #pragma unroll
        for (int it=0;it<2;++it){
          const int Ri = wi*2+it;
          hfrag af[4];
          #pragma unroll
          for (int ds=0;ds<4;++ds) af[ds] = *(const hfrag*)&W16f[(Ri*4+ds)*512 + lane*8];
          #pragma unroll
          for (int jj=0;jj<2;++jj){
            ffrag acc = (ffrag){0.f,0.f,0.f,0.f};
            #pragma unroll
            for (int ds=0;ds<4;++ds) acc = MFMA16(af[ds], bf[jj][ds], acc);
            const int src = (wj*2+jj)*16 + l15;
            const int sds = src>>5, s16 = 16*((src>>3)&3), s7 = src&7;
            #pragma unroll
            for (int r=0;r<4;++r)
              m16[((Ri*4 + sds)*64 + 4*g + r + s16)*8 + s7] = (_Float16)acc[r];
          }
        }
      }
      __syncthreads();
      if (l < 3){
        #pragma unroll
        for (int i=0;i<2;++i){
          const int c = i*16 + w16;
          GLOAD16(wg16 + (l+1)*16384 + c*512 + lane*8, &W16f[c*512]);
        }
      }
      {
        hfrag bf[2][4];
        float bgv[2];
        #pragma unroll
        for (int jj=0;jj<2;++jj){
          const int jg = wj*2+jj;
          #pragma unroll
          for (int ds=0;ds<4;++ds) bf[jj][ds] = *(const hfrag*)&m16[(jg*4+ds)*512 + lane*8];
          bgv[jj] = bg[l*DD + jg*16 + l15];
        }
        #pragma unroll
        for (int it=0;it<2;++it){
          const int Ri = wi*2+it;
          hfrag af[4];
          #pragma unroll
          for (int ds=0;ds<4;++ds) af[ds] = *(const hfrag*)&A16[(Ri*4+ds)*512 + lane*8];
          #pragma unroll
          for (int jj=0;jj<2;++jj){
            ffrag acc = (ffrag){0.f,0.f,0.f,0.f};
            #pragma unroll
            for (int ds=0;ds<4;++ds) acc = MFMA16(af[ds], bf[jj][ds], acc);
            const int dout = (wj*2+jj)*16 + l15;
            if (l < 3){
              const int dds = dout>>5, d16 = 16*((dout>>3)&3), d7 = dout&7;
              #pragma unroll
              for (int r=0;r<4;++r){
                float v = tanh_fast(acc[r] + bgv[jj]);
                h16[((Ri*4 + dds)*64 + 4*g + r + d16)*8 + d7] = (_Float16)v;
              }
            } else {
              #pragma unroll
              for (int r=0;r<4;++r){
                float v = tanh_fast(acc[r] + bgv[jj]);
                out[((size_t)b*128 + Ri*16 + 4*g + r)*(2*DD) + dout] = v;
              }
            }
          }
        }
      }
      __syncthreads();
    }
  } else {
    // ---------------- projection role (2 rows/thread) ----------------
    const int idx  = bid - 64;
    const int mode = idx >> 6;
    const int row0 = (idx & 63) * 128;
    const float* W    = (mode==0) ? Wq : (mode==1) ? Wk : Wv;
    const float* bias = (mode==0) ? bq_ : (mode==1) ? bk_ : bv_;
    float* Xs  = (float*)Lm;
    float* Ws2 = (float*)(Lm + 67584);

    #pragma unroll
    for (int i=0;i<4;++i){
      int i2 = i*1024 + tid;
      int r = i2>>5, c4 = (i2&31)<<2;
      *(float4*)&Ws2[r*132+c4] = *(const float4*)&W[r*DD + c4];
      *(float4*)&Xs [r*132+c4] = *(const float4*)&x[(size_t)(row0+r)*DD + c4];
    }
    __syncthreads();

    const int r0 = (tid>>4)*2;
    const int cg = tid&15;
    const int c0 = cg*8;
    float acc[2][8];
    #pragma unroll
    for (int t=0;t<2;++t)
      #pragma unroll
      for (int m=0;m<8;++m) acc[t][m]=0.f;
    for (int kk=0;kk<128;kk+=4){
      float a[2][4];
      #pragma unroll
      for (int t=0;t<2;++t) *(float4*)a[t] = *(float4*)&Xs[(r0+t)*132+kk];
      #pragma unroll
      for (int j=0;j<4;++j){
        float w[8];
        *(float4*)&w[0] = *(float4*)&Ws2[(kk+j)*132+c0];
        *(float4*)&w[4] = *(float4*)&Ws2[(kk+j)*132+c0+4];
        #pragma unroll
        for (int t=0;t<2;++t)
          #pragma unroll
          for (int m=0;m<8;++m) acc[t][m] += a[t][j]*w[m];
      }
    }
    #pragma unroll
    for (int t=0;t<2;++t){
      const int row = row0 + r0 + t;
      float val[8];
      #pragma unroll
      for (int m=0;m<8;++m) val[m] = acc[t][m] + bias[c0+m];
      if (mode == 0) {
        hfrag h;
        #pragma unroll
        for (int m=0;m<8;++m) h[m] = (_Float16)val[m];
        *(hfrag*)&q16[(size_t)row*DD + c0] = h;
      } else if (mode == 1) {
        hfrag h;
        #pragma unroll
        for (int m=0;m<8;++m) h[m] = (_Float16)val[m];
        int R = row>>4, l15r = row&15, dsx = cg>>2, gx = cg&3;
        *(hfrag*)&k16[((size_t)(R*4+dsx)*64 + l15r + 16*gx)*8] = h;
      } else {
        int C = row>>5, kloc = row&31;
        int gx = (kloc&15)>>2;
        int jx = ((kloc>>4)<<2) | (kloc&3);
        #pragma unroll
        for (int m=0;m<8;++m){
          int d = c0+m;
          vT[((size_t)(C*8 + (d>>4))*64 + (d&15) + 16*gx)*8 + jx] = (_Float16)val[m];
        }
      }
    }
  }
}

// =====================================================================
// k_flash4b: flash4 with per-qb SM->PV interleave. Same ops, reassociated:
// SM(qb0); PV(qb0); SM(qb1); PV(qb1) — qb1's softmax VALU is independent of
// qb0's PV MFMA/ds_read chain, giving the scheduler cross-phase ILP within
// each wave (m214 r289 mechanism). Numerics identical to flash4.
// =====================================================================
__global__ __launch_bounds__(512,2) void k_flash4b(
    const _Float16* __restrict__ q16, const _Float16* __restrict__ k16f,
    const _Float16* __restrict__ vTf,
    _Float16* __restrict__ Opart, float* __restrict__ pm, float* __restrict__ pl)
{
  __shared__ _Float16 Kb[2][8192];
  __shared__ _Float16 Vb[2][8192];
  const int tid  = threadIdx.x;
  const int lane = tid & 63;
  const int w8   = tid >> 6;
  const int l15  = lane & 15;
  const int g    = lane >> 4;
  const int qt   = blockIdx.x >> 3;
  const int sp   = blockIdx.x & 7;
  const int q0   = qt*256 + w8*32;

  hfrag qf[2][4];
  #pragma unroll
  for (int qb=0;qb<2;++qb)
    #pragma unroll
    for (int ds=0;ds<4;++ds)
      qf[qb][ds] = *(const hfrag*)&q16[(size_t)(q0+16*qb+l15)*DD + 32*ds + 8*g];

  float mrun[2] = {-1e30f,-1e30f}, lrun[2] = {0.f,0.f};
  ffrag o[2][8];
  #pragma unroll
  for (int qb=0;qb<2;++qb)
    #pragma unroll
    for (int nt=0;nt<8;++nt) o[qb][nt] = (ffrag){0.f,0.f,0.f,0.f};

  const size_t kbase = (size_t)(sp*1024)*DD;
  {
    const _Float16* Ks = k16f + kbase;
    const _Float16* Vs = vTf  + kbase;
    #pragma unroll
    for (int j=0;j<2;++j){
      const int c = w8*2 + j;
      GLOAD16(Ks + c*512 + lane*8, &Kb[0][c*512]);
      GLOAD16(Vs + c*512 + lane*8, &Vb[0][c*512]);
    }
  }
  __syncthreads();

  int cur = 0;
  for (int t=0; t<16; ++t){
    if (t < 15){
      const _Float16* Ks = k16f + kbase + (size_t)(t+1)*64*DD;
      const _Float16* Vs = vTf  + kbase + (size_t)(t+1)*64*DD;
      #pragma unroll
      for (int j=0;j<2;++j){
        const int c = w8*2 + j;
        GLOAD16(Ks + c*512 + lane*8, &Kb[cur^1][c*512]);
        GLOAD16(Vs + c*512 + lane*8, &Vb[cur^1][c*512]);
      }
    }

    // ---- QK^T for both q-halves (shared K fragments) ----
    ffrag s2[2][4];
    #pragma unroll
    for (int qb=0;qb<2;++qb)
      #pragma unroll
      for (int mt=0;mt<4;++mt) s2[qb][mt] = (ffrag){0.f,0.f,0.f,0.f};
    __builtin_amdgcn_s_setprio(1);
    #pragma unroll
    for (int mt=0;mt<4;++mt)
      #pragma unroll
      for (int ds=0;ds<4;++ds){
        hfrag kf = *(const hfrag*)&Kb[cur][(mt*4+ds)*512 + lane*8];
        s2[0][mt] = MFMA16(kf, qf[0][ds], s2[0][mt]);
        s2[1][mt] = MFMA16(kf, qf[1][ds], s2[1][mt]);
      }
    __builtin_amdgcn_s_setprio(0);

    // ---- interleaved per-qb: SM(qb) then PV(qb); qb1's SM overlaps qb0's PV ----
    #pragma unroll
    for (int qb=0;qb<2;++qb){
      // softmax
      float tmax = -1e30f;
      #pragma unroll
      for (int mt=0;mt<4;++mt)
        tmax = fmaxf(tmax, fmaxf(fmaxf(s2[qb][mt][0], s2[qb][mt][1]),
                                 fmaxf(s2[qb][mt][2], s2[qb][mt][3])));
      tmax = fmaxf(tmax, __shfl_xor(tmax,16));
      tmax = fmaxf(tmax, __shfl_xor(tmax,32));
      const float mnew = fmaxf(mrun[qb], tmax);
      float psum = 0.f;
      #pragma unroll
      for (int mt=0;mt<4;++mt)
        #pragma unroll
        for (int r=0;r<4;++r){ float e = __expf(s2[qb][mt][r]-mnew); s2[qb][mt][r]=e; psum += e; }
      psum += __shfl_xor(psum,16);
      psum += __shfl_xor(psum,32);
      if (__any(mnew > mrun[qb])){
        const float sc = __expf(mrun[qb]-mnew);
        lrun[qb] = lrun[qb]*sc + psum;
        mrun[qb] = mnew;
        #pragma unroll
        for (int r=0;r<4;++r){
          const float scr = __shfl(sc, 4*g+r);
          #pragma unroll
          for (int nt=0;nt<8;++nt) o[qb][nt][r] *= scr;
        }
      } else {
        lrun[qb] += psum;
      }
      // PV for this qb
      __builtin_amdgcn_s_setprio(1);
      #pragma unroll
      for (int c2=0;c2<2;++c2){
        hfrag pf;
        #pragma unroll
        for (int j=0;j<8;++j) pf[j] = (_Float16)s2[qb][2*c2+(j>>2)][j&3];
        #pragma unroll
        for (int nt=0;nt<8;++nt){
          hfrag vf = *(const hfrag*)&Vb[cur][(c2*8+nt)*512 + lane*8];
          o[qb][nt] = MFMA16(pf, vf, o[qb][nt]);
        }
      }
      __builtin_amdgcn_s_setprio(0);
    }

    __syncthreads();
    cur ^= 1;
  }

  #pragma unroll
  for (int qb=0;qb<2;++qb){
    #pragma unroll
    for (int r=0;r<4;++r){
      _Float16* dst = &Opart[((size_t)sp*TT + q0 + 16*qb + 4*g + r)*DD];
      #pragma unroll
      for (int nt=0;nt<8;++nt)
        dst[16*nt + l15] = (_Float16)o[qb][nt][r];
    }
    if (g==0){
      pm[(size_t)sp*TT + q0 + 16*qb + l15] = mrun[qb];
      pl[(size_t)sp*TT + q0 + 16*qb + l15] = lrun[qb];
    }
  }
}

// final GEMM with inline 8-way softmax combine on the A-load (proven).
__global__ __launch_bounds__(256) void k_gemm_final(const _Float16* __restrict__ Opart,
                                                    const float* __restrict__ pm, const float* __restrict__ pl,
                                                    const float* __restrict__ W2, const float* __restrict__ b2,
                                                    float* __restrict__ out) {
  __shared__ float As[32*132];
  __shared__ float Ws[128*132];
  int tid = threadIdx.x;
  int row0 = blockIdx.x*32;
  #pragma unroll
  for (int i=0;i<4;i++){
    int idx = i*256+tid;
    int r = idx>>5, c4 = (idx&31)<<2;
    int t = row0 + r;
    float ms[8], ls[8];
    #pragma unroll
    for (int s=0;s<8;++s){ ms[s]=pm[(size_t)s*TT+t]; ls[s]=pl[(size_t)s*TT+t]; }
    float mx = ms[0];
    #pragma unroll
    for (int s=1;s<8;++s) mx = fmaxf(mx, ms[s]);
    float es[8]; float den = 0.f;
    #pragma unroll
    for (int s=0;s<8;++s){ es[s]=__expf(ms[s]-mx); den += ls[s]*es[s]; }
    float4 vv = {0.f,0.f,0.f,0.f};
    #pragma unroll
    for (int s=0;s<8;++s){
      float us = es[s]/den;
      h4 a = *(const h4*)&Opart[((size_t)s*TT + t)*DD + c4];
      vv.x += us*(float)a[0]; vv.y += us*(float)a[1];
      vv.z += us*(float)a[2]; vv.w += us*(float)a[3];
    }
    *(float4*)&As[r*132+c4] = vv;
  }
  #pragma unroll
  for (int i=0;i<16;i++){
    int idx = i*256+tid;
    int r = idx>>5, c4 = (idx&31)<<2;
    *(float4*)&Ws[r*132+c4] = *(const float4*)&W2[r*DD + c4];
  }
  __syncthreads();
  int rg = tid>>4, cg = tid&15;
  int r0 = rg*2, c0 = cg*8;
  float acc[2][8];
  #pragma unroll
  for (int a=0;a<2;a++)
    #pragma unroll
    for (int b=0;b<8;b++) acc[a][b]=0.f;
  for (int kk=0;kk<128;kk+=4){
    float a0[4], a1[4];
    *(float4*)a0 = *(float4*)&As[r0*132+kk];
    *(float4*)a1 = *(float4*)&As[(r0+1)*132+kk];
    #pragma unroll
    for (int j=0;j<4;j++){
      float w[8];
      *(float4*)&w[0] = *(float4*)&Ws[(kk+j)*132+c0];
      *(float4*)&w[4] = *(float4*)&Ws[(kk+j)*132+c0+4];
      #pragma unroll
      for (int m=0;m<8;m++){
        acc[0][m] += a0[j]*w[m];
        acc[1][m] += a1[j]*w[m];
      }
    }
  }
  #pragma unroll
  for (int a=0;a<2;a++){
    float outv[8];
    #pragma unroll
    for (int m=0;m<8;m++) outv[m] = acc[a][m] + b2[c0+m];
    float* dst = &out[(size_t)(row0+r0+a)*(2*DD) + DD + c0];
    *(float4*)&dst[0] = *(float4*)&outv[0];
    *(float4*)&dst[4] = *(float4*)&outv[4];
  }
}

extern "C" void kernel_launch(void* const* d_in, const int* in_sizes, int n_in,
                              void* d_out, int out_size, void* d_ws, size_t ws_size,
                              hipStream_t stream) {
  const float* x  = (const float*)d_in[0];
  const int* edges = (const int*)d_in[1];
  const float* Wg = (const float*)d_in[2];
  const float* bg = (const float*)d_in[3];
  const float* Wq = (const float*)d_in[4];
  const float* bq = (const float*)d_in[5];
  const float* Wk = (const float*)d_in[6];
  const float* bk = (const float*)d_in[7];
  const float* Wv = (const float*)d_in[8];
  const float* bv = (const float*)d_in[9];
  const float* Wo = (const float*)d_in[10];
  const float* bo = (const float*)d_in[11];
  const float* Wc = (const float*)d_in[12];
  const float* bc = (const float*)d_in[13];
  float* out = (float*)d_out;
  char* ws = (char*)d_ws;

  _Float16* wg16 = (_Float16*)(ws + WS_WG16);
  float* W2  = (float*)(ws + WS_W2);
  float* b2  = (float*)(ws + WS_B2);
  float* pm  = (float*)(ws + WS_PM);
  float* pl  = (float*)(ws + WS_PL);
  _Float16* Opart = (_Float16*)(ws + WS_OPART);
  _Float16* q16 = (_Float16*)(ws + WS_Q16);
  _Float16* k16 = (_Float16*)(ws + WS_K16);
  _Float16* vT  = (_Float16*)(ws + WS_VT);

  k_prep<<<8,512,0,stream>>>(Wg, Wo, bo, Wc, bc, wg16, W2, b2);
  fused_pre<<<256,1024,0,stream>>>(x, edges, wg16, bg, Wq, bq, Wk, bk, Wv, bv,
                                   q16, k16, vT, out);
  k_flash4b<<<256,512,0,stream>>>(q16, k16, vT, Opart, pm, pl);
  k_gemm_final<<<256,256,0,stream>>>(Opart, pm, pl, W2, b2, out);
}

// Round 17
// 103.001 us; speedup vs baseline: 1.0102x; 1.0102x over previous
//
#include <hip/hip_runtime.h>
#include <math.h>

#define TT 8192
#define DD 128
#define GB 64
#define GN 128
#define GE 2048

// ---- workspace layout (bytes) ----
#define WS_WG16    0u            // 128KB: 4 x 16384 f16 frag-order GCN weights
#define WS_W2      (644u<<10)    // 128*128 f32
#define WS_B2      (708u<<10)    // 128 f32
#define WS_Q16     (1u<<20)      // 2MB f16
#define WS_K16     (3u<<20)      // 2MB f16 frag-order
#define WS_VT      (5u<<20)      // 2MB f16 frag-order (kappa)
#define WS_OPART   (7u<<20)      // 16MB: 8 x 8192 x 128 f16 partials
#define WS_PM      (23u<<20)     // 8*8192 f32
#define WS_PL      ((23u<<20)+(256u<<10))

typedef _Float16 hfrag  __attribute__((ext_vector_type(8)));
typedef _Float16 h4     __attribute__((ext_vector_type(4)));
typedef float    ffrag  __attribute__((ext_vector_type(4)));

#define MFMA16(a,b,c) __builtin_amdgcn_mfma_f32_16x16x32_f16((a),(b),(c),0,0,0)

typedef __attribute__((address_space(1))) unsigned int gu32_t;
typedef __attribute__((address_space(3))) unsigned int lu32_t;
#define GLOAD16(gp, lp) __builtin_amdgcn_global_load_lds((gu32_t*)(const void*)(gp), (lu32_t*)(void*)(lp), 16, 0, 0)

// fragment-order element index (proven): A-frag = fidx(i,k); B-frag = fidx(j,k)
__device__ __forceinline__ int fidx(int r_, int c_) {
  return (((r_>>4)*4 + (c_>>5))*64 + (r_&15) + 16*((c_>>3)&3))*8 + (c_&7);
}

__device__ __forceinline__ float tanh_fast(float x) {
  float e = __expf(2.f*x);
  return 1.f - 2.f/(e+1.f);
}

// =====================================================================
// k_prep: 8 blocks x 512 threads (unchanged, proven).
// =====================================================================
__global__ __launch_bounds__(512) void k_prep(const float* __restrict__ Wg,
                                              const float* __restrict__ Wo, const float* __restrict__ bo,
                                              const float* __restrict__ Wc, const float* __restrict__ bc,
                                              _Float16* __restrict__ wg16,
                                              float* __restrict__ W2, float* __restrict__ b2) {
  __shared__ float Wcs[128*128];
  const int tid = threadIdx.x;
  const int bid = blockIdx.x;
  if (bid < 4) {
    #pragma unroll
    for (int i=0;i<32;++i){
      int i2 = i*512 + tid;
      Wcs[i2] = Wc[i2] + Wc[i2 + 16384];
    }
    __syncthreads();
    const int r  = tid>>4;
    const int c0 = (tid&15)*8;
    const int ig = bid*32 + r;
    float acc[8];
    #pragma unroll
    for (int m=0;m<8;++m) acc[m]=0.f;
    for (int k=0;k<128;++k){
      float wo = Wo[ig*DD + k];
      #pragma unroll
      for (int m=0;m<8;++m) acc[m] += wo*Wcs[k*128 + c0 + m];
    }
    #pragma unroll
    for (int m=0;m<8;++m) W2[ig*DD + c0 + m] = acc[m];
    if (bid == 0){
      __syncthreads();
      if (tid < 128){
        float s = bc[tid];
        for (int k=0;k<128;++k) s += bo[k]*Wcs[k*128 + tid];
        b2[tid] = s;
      }
    }
  } else {
    const int l = bid - 4;
    const float* Wl = Wg + l*DD*DD;
    _Float16* dst = wg16 + l*16384;
    #pragma unroll
    for (int i=0;i<8;++i){
      int i4 = i*512 + tid;
      int k = i4>>5, i0 = (i4&31)<<2;
      float4 v = *(const float4*)&Wl[k*DD + i0];
      dst[fidx(i0+0,k)] = (_Float16)v.x;
      dst[fidx(i0+1,k)] = (_Float16)v.y;
      dst[fidx(i0+2,k)] = (_Float16)v.z;
      dst[fidx(i0+3,k)] = (_Float16)v.w;
    }
  }
}

// =====================================================================
// fused_pre: 256 blocks x 1024 threads (unchanged from r15, proven).
// =====================================================================
__global__ __launch_bounds__(1024,1) void fused_pre(
    const float* __restrict__ x, const int* __restrict__ edges,
    const _Float16* __restrict__ wg16, const float* __restrict__ bg,
    const float* __restrict__ Wq, const float* __restrict__ bq_,
    const float* __restrict__ Wk, const float* __restrict__ bk_,
    const float* __restrict__ Wv, const float* __restrict__ bv_,
    _Float16* __restrict__ q16, _Float16* __restrict__ k16, _Float16* __restrict__ vT,
    float* __restrict__ out)
{
  __shared__ __align__(16) char Lm[135168];
  const int tid  = threadIdx.x;
  const int bid  = blockIdx.x;

  if (bid < 64) {
    // ---------------- GCN role (16 warps) ----------------
    float*    Af   = (float*)Lm;
    _Float16* W16f = (_Float16*)Lm;
    _Float16* m16  = (_Float16*)(Lm + 32768);
    _Float16* h16  = (_Float16*)(Lm + 65536);
    _Float16* A16  = (_Float16*)(Lm + 98304);
    int*      cnt  = (int*)(Lm + 131072);
    float*    nrm  = (float*)(Lm + 131584);

    const int lane = tid & 63;
    const int w16  = tid >> 6;
    const int l15  = lane & 15;
    const int g    = lane >> 4;
    const int wi   = w16 >> 2;
    const int wj   = w16 & 3;
    const int b    = bid;
    const int* eg  = edges + b*2*GE;

    #pragma unroll
    for (int i=0;i<4;++i) ((float4*)Af)[i*1024 + tid] = (float4){0.f,0.f,0.f,0.f};
    if (tid < 128) cnt[tid] = 0;
    __syncthreads();
    #pragma unroll
    for (int i=0;i<2;++i) atomicAdd(&cnt[eg[GE + i*1024 + tid]], 1);
    __syncthreads();
    if (tid < 128) nrm[tid] = rsqrtf(1.f + (float)cnt[tid]);
    __syncthreads();
    #pragma unroll
    for (int i=0;i<2;++i){
      int s = eg[i*1024 + tid], d = eg[GE + i*1024 + tid];
      atomicAdd(&Af[d*128 + s], nrm[s]*nrm[d]);
    }
    __syncthreads();
    if (tid < 128) Af[tid*128 + tid] += nrm[tid]*nrm[tid];
    __syncthreads();
    #pragma unroll
    for (int i=0;i<4;++i){
      int i4 = i*1024 + tid;
      float4 v = ((const float4*)Af)[i4];
      int dst = i4>>5, s4 = (i4&31)<<2;
      h4 t; t[0]=(_Float16)v.x; t[1]=(_Float16)v.y; t[2]=(_Float16)v.z; t[3]=(_Float16)v.w;
      *(h4*)&A16[fidx(dst, s4)] = t;
    }
    #pragma unroll
    for (int i=0;i<4;++i){
      int i4 = i*1024 + tid;
      int n = i4>>5, k4 = (i4&31)<<2;
      float4 v = *(const float4*)&x[((size_t)b*128 + n)*128 + k4];
      h4 t; t[0]=(_Float16)v.x; t[1]=(_Float16)v.y; t[2]=(_Float16)v.z; t[3]=(_Float16)v.w;
      *(h4*)&h16[fidx(n, k4)] = t;
    }
    __syncthreads();
    #pragma unroll
    for (int i=0;i<2;++i){
      const int c = i*16 + w16;
      GLOAD16(wg16 + c*512 + lane*8, &W16f[c*512]);
    }
    asm volatile("s_waitcnt vmcnt(0)" ::: "memory");
    __syncthreads();

    for (int l=0; l<4; ++l){
      {
        hfrag bf[2][4];
        #pragma unroll
        for (int jj=0;jj<2;++jj){
          const int jg = wj*2+jj;
          #pragma unroll
          for (int ds=0;ds<4;++ds) bf[jj][ds] = *(const hfrag*)&h16[(jg*4+ds)*512 + lane*8];
        }
        #pragma unroll
        for (int it=0;it<2;++it){
          const int Ri = wi*2+it;
          hfrag af[4];
          #pragma unroll
          for (int ds=0;ds<4;++ds) af[ds] = *(const hfrag*)&W16f[(Ri*4+ds)*512 + lane*8];
          #pragma unroll
          for (int jj=0;jj<2;++jj){
            ffrag acc = (ffrag){0.f,0.f,0.f,0.f};
            #pragma unroll
            for (int ds=0;ds<4;++ds) acc = MFMA16(af[ds], bf[jj][ds], acc);
            const int src = (wj*2+jj)*16 + l15;
            const int sds = src>>5, s16 = 16*((src>>3)&3), s7 = src&7;
            #pragma unroll
            for (int r=0;r<4;++r)
              m16[((Ri*4 + sds)*64 + 4*g + r + s16)*8 + s7] = (_Float16)acc[r];
          }
        }
      }
      __syncthreads();
      if (l < 3){
        #pragma unroll
        for (int i=0;i<2;++i){
          const int c = i*16 + w16;
          GLOAD16(wg16 + (l+1)*16384 + c*512 + lane*8, &W16f[c*512]);
        }
      }
      {
        hfrag bf[2][4];
        float bgv[2];
        #pragma unroll
        for (int jj=0;jj<2;++jj){
          const int jg = wj*2+jj;
          #pragma unroll
          for (int ds=0;ds<4;++ds) bf[jj][ds] = *(const hfrag*)&m16[(jg*4+ds)*512 + lane*8];
          bgv[jj] = bg[l*DD + jg*16 + l15];
        }
        #pragma unroll
        for (int it=0;it<2;++it){
          const int Ri = wi*2+it;
          hfrag af[4];
          #pragma unroll
          for (int ds=0;ds<4;++ds) af[ds] = *(const hfrag*)&A16[(Ri*4+ds)*512 + lane*8];
          #pragma unroll
          for (int jj=0;jj<2;++jj){
            ffrag acc = (ffrag){0.f,0.f,0.f,0.f};
            #pragma unroll
            for (int ds=0;ds<4;++ds) acc = MFMA16(af[ds], bf[jj][ds], acc);
            const int dout = (wj*2+jj)*16 + l15;
            if (l < 3){
              const int dds = dout>>5, d16 = 16*((dout>>3)&3), d7 = dout&7;
              #pragma unroll
              for (int r=0;r<4;++r){
                float v = tanh_fast(acc[r] + bgv[jj]);
                h16[((Ri*4 + dds)*64 + 4*g + r + d16)*8 + d7] = (_Float16)v;
              }
            } else {
              #pragma unroll
              for (int r=0;r<4;++r){
                float v = tanh_fast(acc[r] + bgv[jj]);
                out[((size_t)b*128 + Ri*16 + 4*g + r)*(2*DD) + dout] = v;
              }
            }
          }
        }
      }
      __syncthreads();
    }
  } else {
    // ---------------- projection role (2 rows/thread) ----------------
    const int idx  = bid - 64;
    const int mode = idx >> 6;
    const int row0 = (idx & 63) * 128;
    const float* W    = (mode==0) ? Wq : (mode==1) ? Wk : Wv;
    const float* bias = (mode==0) ? bq_ : (mode==1) ? bk_ : bv_;
    float* Xs  = (float*)Lm;
    float* Ws2 = (float*)(Lm + 67584);

    #pragma unroll
    for (int i=0;i<4;++i){
      int i2 = i*1024 + tid;
      int r = i2>>5, c4 = (i2&31)<<2;
      *(float4*)&Ws2[r*132+c4] = *(const float4*)&W[r*DD + c4];
      *(float4*)&Xs [r*132+c4] = *(const float4*)&x[(size_t)(row0+r)*DD + c4];
    }
    __syncthreads();

    const int r0 = (tid>>4)*2;
    const int cg = tid&15;
    const int c0 = cg*8;
    float acc[2][8];
    #pragma unroll
    for (int t=0;t<2;++t)
      #pragma unroll
      for (int m=0;m<8;++m) acc[t][m]=0.f;
    for (int kk=0;kk<128;kk+=4){
      float a[2][4];
      #pragma unroll
      for (int t=0;t<2;++t) *(float4*)a[t] = *(float4*)&Xs[(r0+t)*132+kk];
      #pragma unroll
      for (int j=0;j<4;++j){
        float w[8];
        *(float4*)&w[0] = *(float4*)&Ws2[(kk+j)*132+c0];
        *(float4*)&w[4] = *(float4*)&Ws2[(kk+j)*132+c0+4];
        #pragma unroll
        for (int t=0;t<2;++t)
          #pragma unroll
          for (int m=0;m<8;++m) acc[t][m] += a[t][j]*w[m];
      }
    }
    #pragma unroll
    for (int t=0;t<2;++t){
      const int row = row0 + r0 + t;
      float val[8];
      #pragma unroll
      for (int m=0;m<8;++m) val[m] = acc[t][m] + bias[c0+m];
      if (mode == 0) {
        hfrag h;
        #pragma unroll
        for (int m=0;m<8;++m) h[m] = (_Float16)val[m];
        *(hfrag*)&q16[(size_t)row*DD + c0] = h;
      } else if (mode == 1) {
        hfrag h;
        #pragma unroll
        for (int m=0;m<8;++m) h[m] = (_Float16)val[m];
        int R = row>>4, l15r = row&15, dsx = cg>>2, gx = cg&3;
        *(hfrag*)&k16[((size_t)(R*4+dsx)*64 + l15r + 16*gx)*8] = h;
      } else {
        int C = row>>5, kloc = row&31;
        int gx = (kloc&15)>>2;
        int jx = ((kloc>>4)<<2) | (kloc&3);
        #pragma unroll
        for (int m=0;m<8;++m){
          int d = c0+m;
          vT[((size_t)(C*8 + (d>>4))*64 + (d&15) + 16*gx)*8 + jx] = (_Float16)val[m];
        }
      }
    }
  }
}

// =====================================================================
// k_flash4: 8-warp independent-softmax MFMA flash attention, KS=8, grid 256.
// Proven 62.2us / VGPR 96 / 0 bank conflicts (r6-r10, r15). Verbatim.
// =====================================================================
__global__ __launch_bounds__(512,2) void k_flash4(
    const _Float16* __restrict__ q16, const _Float16* __restrict__ k16f,
    const _Float16* __restrict__ vTf,
    _Float16* __restrict__ Opart, float* __restrict__ pm, float* __restrict__ pl)
{
  __shared__ _Float16 Kb[2][8192];
  __shared__ _Float16 Vb[2][8192];
  const int tid  = threadIdx.x;
  const int lane = tid & 63;
  const int w8   = tid >> 6;
  const int l15  = lane & 15;
  const int g    = lane >> 4;
  const int qt   = blockIdx.x >> 3;
  const int sp   = blockIdx.x & 7;
  const int q0   = qt*256 + w8*32;

  hfrag qf[2][4];
  #pragma unroll
  for (int qb=0;qb<2;++qb)
    #pragma unroll
    for (int ds=0;ds<4;++ds)
      qf[qb][ds] = *(const hfrag*)&q16[(size_t)(q0+16*qb+l15)*DD + 32*ds + 8*g];

  float mrun[2] = {-1e30f,-1e30f}, lrun[2] = {0.f,0.f};
  ffrag o[2][8];
  #pragma unroll
  for (int qb=0;qb<2;++qb)
    #pragma unroll
    for (int nt=0;nt<8;++nt) o[qb][nt] = (ffrag){0.f,0.f,0.f,0.f};

  const size_t kbase = (size_t)(sp*1024)*DD;
  {
    const _Float16* Ks = k16f + kbase;
    const _Float16* Vs = vTf  + kbase;
    #pragma unroll
    for (int j=0;j<2;++j){
      const int c = w8*2 + j;
      GLOAD16(Ks + c*512 + lane*8, &Kb[0][c*512]);
      GLOAD16(Vs + c*512 + lane*8, &Vb[0][c*512]);
    }
  }
  __syncthreads();

  int cur = 0;
  for (int t=0; t<16; ++t){
    if (t < 15){
      const _Float16* Ks = k16f + kbase + (size_t)(t+1)*64*DD;
      const _Float16* Vs = vTf  + kbase + (size_t)(t+1)*64*DD;
      #pragma unroll
      for (int j=0;j<2;++j){
        const int c = w8*2 + j;
        GLOAD16(Ks + c*512 + lane*8, &Kb[cur^1][c*512]);
        GLOAD16(Vs + c*512 + lane*8, &Vb[cur^1][c*512]);
      }
    }

    ffrag s2[2][4];
    #pragma unroll
    for (int qb=0;qb<2;++qb)
      #pragma unroll
      for (int mt=0;mt<4;++mt) s2[qb][mt] = (ffrag){0.f,0.f,0.f,0.f};
    __builtin_amdgcn_s_setprio(1);
    #pragma unroll
    for (int mt=0;mt<4;++mt)
      #pragma unroll
      for (int ds=0;ds<4;++ds){
        hfrag kf = *(const hfrag*)&Kb[cur][(mt*4+ds)*512 + lane*8];
        s2[0][mt] = MFMA16(kf, qf[0][ds], s2[0][mt]);
        s2[1][mt] = MFMA16(kf, qf[1][ds], s2[1][mt]);
      }
    __builtin_amdgcn_s_setprio(0);

    #pragma unroll
    for (int qb=0;qb<2;++qb){
      float tmax = -1e30f;
      #pragma unroll
      for (int mt=0;mt<4;++mt)
        tmax = fmaxf(tmax, fmaxf(fmaxf(s2[qb][mt][0], s2[qb][mt][1]),
                                 fmaxf(s2[qb][mt][2], s2[qb][mt][3])));
      tmax = fmaxf(tmax, __shfl_xor(tmax,16));
      tmax = fmaxf(tmax, __shfl_xor(tmax,32));
      const float mnew = fmaxf(mrun[qb], tmax);
      float psum = 0.f;
      #pragma unroll
      for (int mt=0;mt<4;++mt)
        #pragma unroll
        for (int r=0;r<4;++r){ float e = __expf(s2[qb][mt][r]-mnew); s2[qb][mt][r]=e; psum += e; }
      psum += __shfl_xor(psum,16);
      psum += __shfl_xor(psum,32);
      if (__any(mnew > mrun[qb])){
        const float sc = __expf(mrun[qb]-mnew);
        lrun[qb] = lrun[qb]*sc + psum;
        mrun[qb] = mnew;
        #pragma unroll
        for (int r=0;r<4;++r){
          const float scr = __shfl(sc, 4*g+r);
          #pragma unroll
          for (int nt=0;nt<8;++nt) o[qb][nt][r] *= scr;
        }
      } else {
        lrun[qb] += psum;
      }
    }

    __builtin_amdgcn_s_setprio(1);
    #pragma unroll
    for (int c2=0;c2<2;++c2){
      hfrag pf0, pf1;
      #pragma unroll
      for (int j=0;j<8;++j){
        pf0[j] = (_Float16)s2[0][2*c2+(j>>2)][j&3];
        pf1[j] = (_Float16)s2[1][2*c2+(j>>2)][j&3];
      }
      #pragma unroll
      for (int nt=0;nt<8;++nt){
        hfrag vf = *(const hfrag*)&Vb[cur][(c2*8+nt)*512 + lane*8];
        o[0][nt] = MFMA16(pf0, vf, o[0][nt]);
        o[1][nt] = MFMA16(pf1, vf, o[1][nt]);
      }
    }
    __builtin_amdgcn_s_setprio(0);

    __syncthreads();
    cur ^= 1;
  }

  #pragma unroll
  for (int qb=0;qb<2;++qb){
    #pragma unroll
    for (int r=0;r<4;++r){
      _Float16* dst = &Opart[((size_t)sp*TT + q0 + 16*qb + 4*g + r)*DD];
      #pragma unroll
      for (int nt=0;nt<8;++nt)
        dst[16*nt + l15] = (_Float16)o[qb][nt][r];
    }
    if (g==0){
      pm[(size_t)sp*TT + q0 + 16*qb + l15] = mrun[qb];
      pl[(size_t)sp*TT + q0 + 16*qb + l15] = lrun[qb];
    }
  }
}

// final GEMM with inline 8-way softmax combine on the A-load (proven).
__global__ __launch_bounds__(256) void k_gemm_final(const _Float16* __restrict__ Opart,
                                                    const float* __restrict__ pm, const float* __restrict__ pl,
                                                    const float* __restrict__ W2, const float* __restrict__ b2,
                                                    float* __restrict__ out) {
  __shared__ float As[32*132];
  __shared__ float Ws[128*132];
  int tid = threadIdx.x;
  int row0 = blockIdx.x*32;
  #pragma unroll
  for (int i=0;i<4;i++){
    int idx = i*256+tid;
    int r = idx>>5, c4 = (idx&31)<<2;
    int t = row0 + r;
    float ms[8], ls[8];
    #pragma unroll
    for (int s=0;s<8;++s){ ms[s]=pm[(size_t)s*TT+t]; ls[s]=pl[(size_t)s*TT+t]; }
    float mx = ms[0];
    #pragma unroll
    for (int s=1;s<8;++s) mx = fmaxf(mx, ms[s]);
    float es[8]; float den = 0.f;
    #pragma unroll
    for (int s=0;s<8;++s){ es[s]=__expf(ms[s]-mx); den += ls[s]*es[s]; }
    float4 vv = {0.f,0.f,0.f,0.f};
    #pragma unroll
    for (int s=0;s<8;++s){
      float us = es[s]/den;
      h4 a = *(const h4*)&Opart[((size_t)s*TT + t)*DD + c4];
      vv.x += us*(float)a[0]; vv.y += us*(float)a[1];
      vv.z += us*(float)a[2]; vv.w += us*(float)a[3];
    }
    *(float4*)&As[r*132+c4] = vv;
  }
  #pragma unroll
  for (int i=0;i<16;i++){
    int idx = i*256+tid;
    int r = idx>>5, c4 = (idx&31)<<2;
    *(float4*)&Ws[r*132+c4] = *(const float4*)&W2[r*DD + c4];
  }
  __syncthreads();
  int rg = tid>>4, cg = tid&15;
  int r0 = rg*2, c0 = cg*8;
  float acc[2][8];
  #pragma unroll
  for (int a=0;a<2;a++)
    #pragma unroll
    for (int b=0;b<8;b++) acc[a][b]=0.f;
  for (int kk=0;kk<128;kk+=4){
    float a0[4], a1[4];
    *(float4*)a0 = *(float4*)&As[r0*132+kk];
    *(float4*)a1 = *(float4*)&As[(r0+1)*132+kk];
    #pragma unroll
    for (int j=0;j<4;j++){
      float w[8];
      *(float4*)&w[0] = *(float4*)&Ws[(kk+j)*132+c0];
      *(float4*)&w[4] = *(float4*)&Ws[(kk+j)*132+c0+4];
      #pragma unroll
      for (int m=0;m<8;m++){
        acc[0][m] += a0[j]*w[m];
        acc[1][m] += a1[j]*w[m];
      }
    }
  }
  #pragma unroll
  for (int a=0;a<2;a++){
    float outv[8];
    #pragma unroll
    for (int m=0;m<8;m++) outv[m] = acc[a][m] + b2[c0+m];
    float* dst = &out[(size_t)(row0+r0+a)*(2*DD) + DD + c0];
    *(float4*)&dst[0] = *(float4*)&outv[0];
    *(float4*)&dst[4] = *(float4*)&outv[4];
  }
}

extern "C" void kernel_launch(void* const* d_in, const int* in_sizes, int n_in,
                              void* d_out, int out_size, void* d_ws, size_t ws_size,
                              hipStream_t stream) {
  const float* x  = (const float*)d_in[0];
  const int* edges = (const int*)d_in[1];
  const float* Wg = (const float*)d_in[2];
  const float* bg = (const float*)d_in[3];
  const float* Wq = (const float*)d_in[4];
  const float* bq = (const float*)d_in[5];
  const float* Wk = (const float*)d_in[6];
  const float* bk = (const float*)d_in[7];
  const float* Wv = (const float*)d_in[8];
  const float* bv = (const float*)d_in[9];
  const float* Wo = (const float*)d_in[10];
  const float* bo = (const float*)d_in[11];
  const float* Wc = (const float*)d_in[12];
  const float* bc = (const float*)d_in[13];
  float* out = (float*)d_out;
  char* ws = (char*)d_ws;

  _Float16* wg16 = (_Float16*)(ws + WS_WG16);
  float* W2  = (float*)(ws + WS_W2);
  float* b2  = (float*)(ws + WS_B2);
  float* pm  = (float*)(ws + WS_PM);
  float* pl  = (float*)(ws + WS_PL);
  _Float16* Opart = (_Float16*)(ws + WS_OPART);
  _Float16* q16 = (_Float16*)(ws + WS_Q16);
  _Float16* k16 = (_Float16*)(ws + WS_K16);
  _Float16* vT  = (_Float16*)(ws + WS_VT);

  k_prep<<<8,512,0,stream>>>(Wg, Wo, bo, Wc, bc, wg16, W2, b2);
  fused_pre<<<256,1024,0,stream>>>(x, edges, wg16, bg, Wq, bq, Wk, bk, Wv, bv,
                                   q16, k16, vT, out);
  k_flash4<<<256,512,0,stream>>>(q16, k16, vT, Opart, pm, pl);
  k_gemm_final<<<256,256,0,stream>>>(Opart, pm, pl, W2, b2, out);
}